// Round 2
// baseline (693.385 us; speedup 1.0000x reference)
//
#include <hip/hip_runtime.h>

#define BH 64            // B*H heads
#define SEQ 8192
#define DK 128
#define DV 128
#define CS 32            // s-rows per LDS stage
#define LR 72            // LDS row pitch in f16 (144 B); only 64 B live -> swizzle space

typedef _Float16 f16;
typedef _Float16 f16x2 __attribute__((ext_vector_type(2)));
typedef _Float16 f16x8 __attribute__((ext_vector_type(8)));
typedef float f32x4 __attribute__((ext_vector_type(4)));

// Phase 1: per (head, s-chunk) block of 512 threads (8 waves). Each wave owns 32
// of the 256 output cols (0..127 = phi^T V, 128..255 = phi^T phi).
// v2: CS=32 two-deep register double-buffer + raw lgkm-only barriers (no vmcnt
// drain) so global loads stay in flight across the whole stage; dwordx4 loads
// with in-register 2x4 transpose; XOR-swizzled LDS (2-way max on write+read).
template <int NC, bool PARTIAL>
__global__ __launch_bounds__(512, 4) void delta_phase1(
    const float* __restrict__ Kg, const float* __restrict__ Vg,
    float* __restrict__ dstP,   // PARTIAL: ws partial base ; atomic: newM
    float* __restrict__ dstG,   // PARTIAL: unused         ; atomic: Gws
    float* __restrict__ newZ)
{
  __shared__ f16 phi_lds[DK * LR];  // [feat][s] transposed, f16, swizzled
  __shared__ f16 v_lds[DV * LR];

  constexpr int SC  = SEQ / NC;   // s-rows per block
  constexpr int NST = SC / CS;    // stages (32 for NC=8)
  static_assert(NST % 2 == 0, "double-buffer needs even stage count");

  const int chunk = blockIdx.x;
  const int bh    = blockIdx.y;
  const int tid   = threadIdx.x;
  const int wave  = tid >> 6;    // 0..7
  const int lane  = tid & 63;
  const int c32   = lane & 31;
  const int chi   = lane >> 5;   // 0/1
  const int f15_  = lane & 15;
  const int quad  = lane >> 4;   // 0..3

  const float* Kh = Kg + ((size_t)bh * SEQ + (size_t)chunk * SC) * DK;
  const float* Vh = Vg + ((size_t)bh * SEQ + (size_t)chunk * SC) * DV;

  const int srow0    = wave * 4 + chi * 2;   // this thread's 2 s-rows per stage
  const int featbase = c32 * 4;              // this thread's 4 feats
  const int swx      = ((c32 >> 1) & 7) << 3;  // write-side swizzle (feat>>3 == c32>>1)

  f32x4 acc[8][2];   // 8 row-tiles x 2 col-tiles of 16x16 (wave owns 32 cols)
#pragma unroll
  for (int r = 0; r < 8; ++r)
#pragma unroll
    for (int c = 0; c < 2; ++c)
      acc[r][c] = (f32x4){0.f, 0.f, 0.f, 0.f};

  float zacc[4] = {0.f, 0.f, 0.f, 0.f};  // colsum partials, feat = featbase + ff

  // Two named register banks (rule: no runtime bank index -> stays in VGPRs).
  f32x4 ka0, ka1, va0, va1;   // bank A: K rows srow0/srow0+1, V same
  f32x4 kb0, kb1, vb0, vb1;   // bank B

#define LOAD_STAGE(ST, K0, K1, V0, V1)                                   \
  {                                                                      \
    const float* kp_ = Kh + ((size_t)(ST) * CS + srow0) * DK + featbase; \
    const float* vp_ = Vh + ((size_t)(ST) * CS + srow0) * DV + featbase; \
    K0 = *(const f32x4*)kp_;                                             \
    K1 = *(const f32x4*)(kp_ + DK);                                      \
    V0 = *(const f32x4*)vp_;                                             \
    V1 = *(const f32x4*)(vp_ + DV);                                      \
  }

  // elu(x)+1 ; transpose in-register (thread owns 2 rows x 4 feats) ; f16x2
  // stores at swizzled [feat][srow0..+1].
#define CONVERT_STORE(K0, K1, V0, V1)                                    \
  {                                                                      \
    _Pragma("unroll")                                                    \
    for (int ff = 0; ff < 4; ++ff) {                                     \
      const int feat = featbase + ff;                                    \
      const float a0 = K0[ff], a1 = K1[ff];                              \
      const float p0 = a0 > 0.f ? a0 + 1.f : __expf(a0);                 \
      const float p1 = a1 > 0.f ? a1 + 1.f : __expf(a1);                 \
      zacc[ff] += p0 + p1;                                               \
      const int idx = (feat * LR + srow0) ^ swx;                         \
      *(f16x2*)&phi_lds[idx] = (f16x2){(f16)p0, (f16)p1};                \
      *(f16x2*)&v_lds[idx]   = (f16x2){(f16)V0[ff], (f16)V1[ff]};        \
    }                                                                    \
  }

  // lgkm-only barrier: orders LDS write->read / read->overwrite without
  // draining outstanding global loads (the point of the pipeline).
#define BAR()                                                            \
  {                                                                      \
    asm volatile("s_waitcnt lgkmcnt(0)" ::: "memory");                   \
    __builtin_amdgcn_s_barrier();                                        \
  }

  // One K=32 MFMA step over this stage's 32 s-rows.
#define MFMA_PHASE()                                                     \
  {                                                                      \
    const f16* bsrc  = (wave < 4) ? v_lds : phi_lds;                     \
    const int  cbase = (wave < 4) ? wave * 32 : wave * 32 - 128;         \
    const int  sb    = quad * 8;                                         \
    __builtin_amdgcn_s_setprio(1);                                       \
    f16x8 bfr[2];                                                        \
    _Pragma("unroll")                                                    \
    for (int c = 0; c < 2; ++c) {                                        \
      const int fB = cbase + c * 16 + f15_;                              \
      bfr[c] = *(const f16x8*)&bsrc[(fB * LR + sb) ^ (((fB >> 3) & 7) << 3)]; \
    }                                                                    \
    _Pragma("unroll")                                                    \
    for (int r = 0; r < 8; ++r) {                                        \
      const int fA = r * 16 + f15_;                                      \
      const f16x8 afr = *(const f16x8*)&phi_lds[(fA * LR + sb) ^ (((fA >> 3) & 7) << 3)]; \
      acc[r][0] = __builtin_amdgcn_mfma_f32_16x16x32_f16(afr, bfr[0], acc[r][0], 0, 0, 0); \
      acc[r][1] = __builtin_amdgcn_mfma_f32_16x16x32_f16(afr, bfr[1], acc[r][1], 0, 0, 0); \
    }                                                                    \
    __builtin_amdgcn_s_setprio(0);                                       \
  }

  LOAD_STAGE(0, ka0, ka1, va0, va1);

  for (int st = 0; st < NST; st += 2) {
    // Issue B-bank loads for stage st+1 BEFORE consuming A: in-flight window
    // spans convert+MFMA+barriers of this stage.
    LOAD_STAGE(st + 1, kb0, kb1, vb0, vb1);
    CONVERT_STORE(ka0, ka1, va0, va1);   // compiler emits counted vmcnt for A only
    BAR();
    MFMA_PHASE();
    BAR();
    if (st + 2 < NST) LOAD_STAGE(st + 2, ka0, ka1, va0, va1);
    CONVERT_STORE(kb0, kb1, vb0, vb1);
    BAR();
    MFMA_PHASE();
    BAR();
  }
#undef LOAD_STAGE
#undef CONVERT_STORE
#undef BAR
#undef MFMA_PHASE

  // Epilogue: C/D layout col=lane&15, row=quad*4+reg
  if (PARTIAL) {
    const size_t pb = (size_t)(bh * NC + chunk) * (128 * 256);
#pragma unroll
    for (int r = 0; r < 8; ++r)
#pragma unroll
      for (int c = 0; c < 2; ++c) {
        const int col = wave * 32 + c * 16 + f15_;
#pragma unroll
        for (int q = 0; q < 4; ++q) {
          const int row = r * 16 + quad * 4 + q;
          dstP[pb + (size_t)row * 256 + col] = acc[r][c][q];
        }
      }
  } else {
    const size_t mb = (size_t)bh * DK * DV;
#pragma unroll
    for (int r = 0; r < 8; ++r)
#pragma unroll
      for (int c = 0; c < 2; ++c) {
        const int col = wave * 32 + c * 16 + f15_;
#pragma unroll
        for (int q = 0; q < 4; ++q) {
          const int row = r * 16 + quad * 4 + q;
          const float v = acc[r][c][q];
          if (col < DV)
            atomicAdd(&dstP[mb + (size_t)row * DV + col], v);
          else
            atomicAdd(&dstG[mb + (size_t)row * DK + (col - DV)], v);
        }
      }
  }
  // z: lanes l and l+32 share feats -> shfl reduce, then one atomic per feat
#pragma unroll
  for (int ff = 0; ff < 4; ++ff) {
    float v = zacc[ff];
    v += __shfl_xor(v, 32, 64);
    if (chi == 0) atomicAdd(&newZ[bh * DK + featbase + ff], v);
  }
}

// Reduce per-chunk partials: newM(cols<128) = M + sum, Gred(cols>=128) = sum.
__global__ __launch_bounds__(256) void delta_reduce(
    const float* __restrict__ Pp, const float* __restrict__ Mg,
    float* __restrict__ newM, float* __restrict__ Gred, int NC)
{
  const int ct  = blockIdx.x;       // 0..7 -> 32-col tile
  const int bh  = blockIdx.y;
  const int tid = threadIdx.x;
  const int col = ct * 32 + (tid & 31);
  const int r0  = tid >> 5;         // 0..7

  float acc[16];
#pragma unroll
  for (int i = 0; i < 16; ++i) acc[i] = 0.f;

  const float* base = Pp + (size_t)(bh * NC) * 32768;
  for (int ch = 0; ch < NC; ++ch) {
    const float* p = base + (size_t)ch * 32768;
#pragma unroll
    for (int i = 0; i < 16; ++i)
      acc[i] += p[(size_t)(r0 + 8 * i) * 256 + col];
  }
  if (col < 128) {
#pragma unroll
    for (int i = 0; i < 16; ++i) {
      const int row = r0 + 8 * i;
      newM[(size_t)bh * 16384 + (size_t)row * 128 + col] =
          Mg[(size_t)bh * 16384 + (size_t)row * 128 + col] + acc[i];
    }
  } else {
#pragma unroll
    for (int i = 0; i < 16; ++i) {
      const int row = r0 + 8 * i;
      Gred[(size_t)bh * 16384 + (size_t)row * 128 + (col - 128)] = acc[i];
    }
  }
}

// newM -= G * M (per head, fp32).
__global__ __launch_bounds__(256) void delta_gm(
    const float* __restrict__ Mg, const float* __restrict__ G, float* __restrict__ newM)
{
  __shared__ float Gs[64 * 129];
  __shared__ float Ms[DK * 32];
  const int sub = blockIdx.x;  // 0..7
  const int bh  = blockIdx.y;
  const int kh  = sub >> 2;    // k half
  const int vt  = sub & 3;     // v tile
  const int tid = threadIdx.x;
  const size_t mb = (size_t)bh * DK * DV;

  for (int i = tid; i < 64 * DK; i += 256)
    Gs[(i >> 7) * 129 + (i & 127)] = G[mb + (size_t)(kh * 64 + (i >> 7)) * DK + (i & 127)];
  for (int i = tid; i < DK * 32; i += 256)
    Ms[i] = Mg[mb + (size_t)(i >> 5) * DV + vt * 32 + (i & 31)];
  __syncthreads();

  const int kl = tid >> 2;
  const int vs = (tid & 3) * 8;
  float a[8];
#pragma unroll
  for (int j = 0; j < 8; ++j) a[j] = 0.f;
  for (int kk = 0; kk < DK; ++kk) {
    const float g = Gs[kl * 129 + kk];
#pragma unroll
    for (int j = 0; j < 8; ++j) a[j] += g * Ms[kk * 32 + vs + j];
  }
  float* dst = &newM[mb + (size_t)(kh * 64 + kl) * DV + vt * 32 + vs];
#pragma unroll
  for (int j = 0; j < 8; ++j) dst[j] -= a[j];
}

extern "C" void kernel_launch(void* const* d_in, const int* in_sizes, int n_in,
                              void* d_out, int out_size, void* d_ws, size_t ws_size,
                              hipStream_t stream) {
  const float* Kg = (const float*)d_in[0];
  const float* Vg = (const float*)d_in[1];
  const float* Mg = (const float*)d_in[2];
  const float* zg = (const float*)d_in[3];
  float* out  = (float*)d_out;
  float* newM = out;                              // BH*DK*DV floats
  float* newZ = out + (size_t)BH * DK * DV;       // BH*DK floats

  const size_t gredF = (size_t)BH * DK * DK;      // 1M floats (4 MB)
  const size_t need8 = ((size_t)BH * 8 * 32768 + gredF) * sizeof(float);  // ~71 MB

  hipMemcpyAsync(newZ, zg, sizeof(float) * (size_t)BH * DK,
                 hipMemcpyDeviceToDevice, stream);

  if (ws_size >= need8) {
    float* Pp   = (float*)d_ws;
    float* Gred = Pp + (size_t)BH * 8 * 32768;
    delta_phase1<8, true><<<dim3(8, BH), 512, 0, stream>>>(Kg, Vg, Pp, nullptr, newZ);
    delta_reduce<<<dim3(8, BH), 256, 0, stream>>>(Pp, Mg, newM, Gred, 8);
    delta_gm<<<dim3(8, BH), 256, 0, stream>>>(Mg, Gred, newM);
  } else {
    // Atomic fallback: newM/Gws pre-initialized, phase1 accumulates in place.
    float* Gws = (float*)d_ws;                    // 4 MB
    hipMemcpyAsync(newM, Mg, sizeof(float) * (size_t)BH * DK * DV,
                   hipMemcpyDeviceToDevice, stream);
    hipMemsetAsync(Gws, 0, sizeof(float) * gredF, stream);
    delta_phase1<8, false><<<dim3(8, BH), 512, 0, stream>>>(Kg, Vg, newM, Gws, newZ);
    delta_gm<<<dim3(8, BH), 256, 0, stream>>>(Mg, Gws, newM);
  }
}

// Round 3
// 564.979 us; speedup vs baseline: 1.2273x; 1.2273x over previous
//
#include <hip/hip_runtime.h>

#define BH 64            // B*H heads
#define SEQ 8192
#define DK 128
#define DV 128
#define CS 64            // s-rows per LDS stage
#define LR 72            // LDS row pitch in f16 (144 B: 16B-aligned rows)

typedef _Float16 f16;
typedef _Float16 f16x4 __attribute__((ext_vector_type(4)));
typedef _Float16 f16x8 __attribute__((ext_vector_type(8)));
typedef float f32x4 __attribute__((ext_vector_type(4)));

// Phase 1: per (head, s-chunk) block of 512 threads (8 waves). Each wave owns 32
// of the 256 output cols (0..127 = phi^T V, 128..255 = phi^T phi).
// v3 = v1 structure (no spill, VGPR=64) + lgkm-only barriers: global prefetch
// loads stay in flight across both per-stage barriers instead of being drained
// by __syncthreads()'s implicit vmcnt(0). Loads issued before the leading
// barrier so the in-flight window spans barrier+MFMA+barrier.
template <int NC, bool PARTIAL>
__global__ __launch_bounds__(512, 4) void delta_phase1(
    const float* __restrict__ Kg, const float* __restrict__ Vg,
    float* __restrict__ dstP,   // PARTIAL: ws partial base ; atomic: newM
    float* __restrict__ dstG,   // PARTIAL: unused         ; atomic: Gws
    float* __restrict__ newZ)
{
  __shared__ f16 phi_lds[DK * LR];  // [feat][s] transposed, f16
  __shared__ f16 v_lds[DV * LR];

  constexpr int SC  = SEQ / NC;   // s-rows per block
  constexpr int NST = SC / CS;    // stages

  const int chunk = blockIdx.x;
  const int bh    = blockIdx.y;
  const int tid   = threadIdx.x;
  const int wave  = tid >> 6;    // 0..7
  const int lane  = tid & 63;
  const int l31   = lane & 31;
  const int lhi   = lane >> 5;   // 0/1
  const int f15_  = lane & 15;
  const int quad  = lane >> 4;   // 0..3

  const float* Kh = Kg + ((size_t)bh * SEQ + (size_t)chunk * SC) * DK;
  const float* Vh = Vg + ((size_t)bh * SEQ + (size_t)chunk * SC) * DV;
  const int srow = wave * 8 + lhi * 4;   // this thread's s-row base within a stage

  f32x4 acc[8][2];   // 8 row-tiles x 2 col-tiles of 16x16 (wave owns 32 cols)
#pragma unroll
  for (int r = 0; r < 8; ++r)
#pragma unroll
    for (int c = 0; c < 2; ++c)
      acc[r][c] = (f32x4){0.f, 0.f, 0.f, 0.f};

  float zacc[4] = {0.f, 0.f, 0.f, 0.f};  // colsum partials, feat = fj*32 + l31

  float kr[16], vr[16];   // prefetch registers for one stage
#define LOAD_STAGE(ST)                                              \
  {                                                                 \
    const float* Ks_ = Kh + (size_t)(ST) * CS * DK;                 \
    const float* Vs_ = Vh + (size_t)(ST) * CS * DV;                 \
    _Pragma("unroll")                                               \
    for (int fj = 0; fj < 4; ++fj) {                                \
      const int feat_ = fj * 32 + l31;                              \
      const float* kp_ = Ks_ + (size_t)srow * DK + feat_;           \
      const float* vp_ = Vs_ + (size_t)srow * DV + feat_;           \
      _Pragma("unroll")                                             \
      for (int j = 0; j < 4; ++j) {                                 \
        kr[fj * 4 + j] = kp_[(size_t)j * DK];                       \
        vr[fj * 4 + j] = vp_[(size_t)j * DV];                       \
      }                                                             \
    }                                                               \
  }

  // lgkm-only barrier: orders LDS write->read / read->overwrite without
  // draining outstanding global loads. (Correctness of this scheme was
  // verified by the R2 run: passed=true with identical barrier macro.)
#define BAR()                                                       \
  {                                                                 \
    asm volatile("s_waitcnt lgkmcnt(0)" ::: "memory");              \
    __builtin_amdgcn_s_barrier();                                   \
  }

  LOAD_STAGE(0);

  for (int st = 0; st < NST; ++st) {
    // Convert + transposed LDS store (consumes prefetch regs of stage st).
#pragma unroll
    for (int fj = 0; fj < 4; ++fj) {
      const int feat = fj * 32 + l31;
      const float a0 = kr[fj * 4 + 0];
      const float a1 = kr[fj * 4 + 1];
      const float a2 = kr[fj * 4 + 2];
      const float a3 = kr[fj * 4 + 3];
      const float p0 = a0 > 0.f ? a0 + 1.f : __expf(a0);  // elu(x)+1
      const float p1 = a1 > 0.f ? a1 + 1.f : __expf(a1);
      const float p2 = a2 > 0.f ? a2 + 1.f : __expf(a2);
      const float p3 = a3 > 0.f ? a3 + 1.f : __expf(a3);
      zacc[fj] += (p0 + p1) + (p2 + p3);
      *(f16x4*)&phi_lds[feat * LR + srow] =
          (f16x4){(f16)p0, (f16)p1, (f16)p2, (f16)p3};
      *(f16x4*)&v_lds[feat * LR + srow] =
          (f16x4){(f16)vr[fj * 4 + 0], (f16)vr[fj * 4 + 1],
                  (f16)vr[fj * 4 + 2], (f16)vr[fj * 4 + 3]};
    }

    // Refill prefetch regs for stage st+1 BEFORE the barrier: loads are in
    // flight across barrier + MFMA + barrier, landing by the next convert.
    // (WAR on kr/vr is safe: convert's VALU ops read operands at issue,
    // before these loads write back.)
    if (st + 1 < NST) LOAD_STAGE(st + 1);

    BAR();   // LDS writes visible to all waves; no vmcnt drain

    // Compute: 2 K-steps of 32 over s.
    const f16* bsrc  = (wave < 4) ? v_lds : phi_lds;
    const int  cbase = (wave < 4) ? wave * 32 : wave * 32 - 128;
    __builtin_amdgcn_s_setprio(1);
#pragma unroll
    for (int ss = 0; ss < 2; ++ss) {
      const int sb = ss * 32 + quad * 8;
      f16x8 bfr[2];
#pragma unroll
      for (int c = 0; c < 2; ++c)
        bfr[c] = *(const f16x8*)&bsrc[(cbase + c * 16 + f15_) * LR + sb];
#pragma unroll
      for (int r = 0; r < 8; ++r) {
        const f16x8 afr = *(const f16x8*)&phi_lds[(r * 16 + f15_) * LR + sb];
        acc[r][0] = __builtin_amdgcn_mfma_f32_16x16x32_f16(afr, bfr[0], acc[r][0], 0, 0, 0);
        acc[r][1] = __builtin_amdgcn_mfma_f32_16x16x32_f16(afr, bfr[1], acc[r][1], 0, 0, 0);
      }
    }
    __builtin_amdgcn_s_setprio(0);

    BAR();   // LDS reads done before next stage's convert overwrites
  }
#undef LOAD_STAGE
#undef BAR

  // Epilogue: C/D layout col=lane&15, row=quad*4+reg
  if (PARTIAL) {
    const size_t pb = (size_t)(bh * NC + chunk) * (128 * 256);
#pragma unroll
    for (int r = 0; r < 8; ++r)
#pragma unroll
      for (int c = 0; c < 2; ++c) {
        const int col = wave * 32 + c * 16 + f15_;
#pragma unroll
        for (int q = 0; q < 4; ++q) {
          const int row = r * 16 + quad * 4 + q;
          dstP[pb + (size_t)row * 256 + col] = acc[r][c][q];
        }
      }
  } else {
    const size_t mb = (size_t)bh * DK * DV;
#pragma unroll
    for (int r = 0; r < 8; ++r)
#pragma unroll
      for (int c = 0; c < 2; ++c) {
        const int col = wave * 32 + c * 16 + f15_;
#pragma unroll
        for (int q = 0; q < 4; ++q) {
          const int row = r * 16 + quad * 4 + q;
          const float v = acc[r][c][q];
          if (col < DV)
            atomicAdd(&dstP[mb + (size_t)row * DV + col], v);
          else
            atomicAdd(&dstG[mb + (size_t)row * DK + (col - DV)], v);
        }
      }
  }
  // z: lanes l and l+32 share feat -> shfl reduce, one atomic per feat per wave
#pragma unroll
  for (int fj = 0; fj < 4; ++fj) {
    float v = zacc[fj];
    v += __shfl_xor(v, 32, 64);
    if (lhi == 0) atomicAdd(&newZ[bh * DK + fj * 32 + l31], v);
  }
}

// Reduce per-chunk partials: newM(cols<128) = M + sum, Gred(cols>=128) = sum.
__global__ __launch_bounds__(256) void delta_reduce(
    const float* __restrict__ Pp, const float* __restrict__ Mg,
    float* __restrict__ newM, float* __restrict__ Gred, int NC)
{
  const int ct  = blockIdx.x;       // 0..7 -> 32-col tile
  const int bh  = blockIdx.y;
  const int tid = threadIdx.x;
  const int col = ct * 32 + (tid & 31);
  const int r0  = tid >> 5;         // 0..7

  float acc[16];
#pragma unroll
  for (int i = 0; i < 16; ++i) acc[i] = 0.f;

  const float* base = Pp + (size_t)(bh * NC) * 32768;
  for (int ch = 0; ch < NC; ++ch) {
    const float* p = base + (size_t)ch * 32768;
#pragma unroll
    for (int i = 0; i < 16; ++i)
      acc[i] += p[(size_t)(r0 + 8 * i) * 256 + col];
  }
  if (col < 128) {
#pragma unroll
    for (int i = 0; i < 16; ++i) {
      const int row = r0 + 8 * i;
      newM[(size_t)bh * 16384 + (size_t)row * 128 + col] =
          Mg[(size_t)bh * 16384 + (size_t)row * 128 + col] + acc[i];
    }
  } else {
#pragma unroll
    for (int i = 0; i < 16; ++i) {
      const int row = r0 + 8 * i;
      Gred[(size_t)bh * 16384 + (size_t)row * 128 + (col - 128)] = acc[i];
    }
  }
}

// newM -= G * M (per head, fp32).
__global__ __launch_bounds__(256) void delta_gm(
    const float* __restrict__ Mg, const float* __restrict__ G, float* __restrict__ newM)
{
  __shared__ float Gs[64 * 129];
  __shared__ float Ms[DK * 32];
  const int sub = blockIdx.x;  // 0..7
  const int bh  = blockIdx.y;
  const int kh  = sub >> 2;    // k half
  const int vt  = sub & 3;     // v tile
  const int tid = threadIdx.x;
  const size_t mb = (size_t)bh * DK * DV;

  for (int i = tid; i < 64 * DK; i += 256)
    Gs[(i >> 7) * 129 + (i & 127)] = G[mb + (size_t)(kh * 64 + (i >> 7)) * DK + (i & 127)];
  for (int i = tid; i < DK * 32; i += 256)
    Ms[i] = Mg[mb + (size_t)(i >> 5) * DV + vt * 32 + (i & 31)];
  __syncthreads();

  const int kl = tid >> 2;
  const int vs = (tid & 3) * 8;
  float a[8];
#pragma unroll
  for (int j = 0; j < 8; ++j) a[j] = 0.f;
  for (int kk = 0; kk < DK; ++kk) {
    const float g = Gs[kl * 129 + kk];
#pragma unroll
    for (int j = 0; j < 8; ++j) a[j] += g * Ms[kk * 32 + vs + j];
  }
  float* dst = &newM[mb + (size_t)(kh * 64 + kl) * DV + vt * 32 + vs];
#pragma unroll
  for (int j = 0; j < 8; ++j) dst[j] -= a[j];
}

extern "C" void kernel_launch(void* const* d_in, const int* in_sizes, int n_in,
                              void* d_out, int out_size, void* d_ws, size_t ws_size,
                              hipStream_t stream) {
  const float* Kg = (const float*)d_in[0];
  const float* Vg = (const float*)d_in[1];
  const float* Mg = (const float*)d_in[2];
  const float* zg = (const float*)d_in[3];
  float* out  = (float*)d_out;
  float* newM = out;                              // BH*DK*DV floats
  float* newZ = out + (size_t)BH * DK * DV;       // BH*DK floats

  const size_t gredF = (size_t)BH * DK * DK;      // 1M floats (4 MB)
  const size_t need8 = ((size_t)BH * 8 * 32768 + gredF) * sizeof(float);  // ~71 MB

  hipMemcpyAsync(newZ, zg, sizeof(float) * (size_t)BH * DK,
                 hipMemcpyDeviceToDevice, stream);

  if (ws_size >= need8) {
    float* Pp   = (float*)d_ws;
    float* Gred = Pp + (size_t)BH * 8 * 32768;
    delta_phase1<8, true><<<dim3(8, BH), 512, 0, stream>>>(Kg, Vg, Pp, nullptr, newZ);
    delta_reduce<<<dim3(8, BH), 256, 0, stream>>>(Pp, Mg, newM, Gred, 8);
    delta_gm<<<dim3(8, BH), 256, 0, stream>>>(Mg, Gred, newM);
  } else {
    // Atomic fallback: newM/Gws pre-initialized, phase1 accumulates in place.
    float* Gws = (float*)d_ws;                    // 4 MB
    hipMemcpyAsync(newM, Mg, sizeof(float) * (size_t)BH * DK * DV,
                   hipMemcpyDeviceToDevice, stream);
    hipMemsetAsync(Gws, 0, sizeof(float) * gredF, stream);
    delta_phase1<8, false><<<dim3(8, BH), 512, 0, stream>>>(Kg, Vg, newM, Gws, newZ);
    delta_gm<<<dim3(8, BH), 256, 0, stream>>>(Mg, Gws, newM);
  }
}